// Round 6
// baseline (153.305 us; speedup 1.0000x reference)
//
#include <hip/hip_runtime.h>

#define H 12
#define S 2048
#define D 768
#define HD 64
#define BATCH 4
#define M_TOT (BATCH * S)   // 8192

typedef __attribute__((ext_vector_type(8))) short bf16x8;
typedef __attribute__((ext_vector_type(4))) float f32x4;
typedef __attribute__((ext_vector_type(16))) float f32x16;

__device__ __forceinline__ ushort f2bf(float f) {
  unsigned int x = __float_as_uint(f);
  x += 0x7fffu + ((x >> 16) & 1u);
  return (ushort)(x >> 16);
}

__device__ __forceinline__ uint cvt_pk_bf16(float lo, float hi) {
  uint r;
  asm("v_cvt_pk_bf16_f32 %0, %1, %2" : "=v"(r) : "v"(lo), "v"(hi));
  return r;
}

// v_permlane32_swap_b32 a,b : a[i>=32] <- b_old[i-32] ; b[i<32] <- a_old[i+32]
__device__ __forceinline__ void plane32swap(uint& a, uint& b) {
  asm volatile("v_permlane32_swap_b32 %0, %1" : "+v"(a), "+v"(b));
}

__device__ __forceinline__ void gload_lds16(const void* gsrc, void* lds) {
  __builtin_amdgcn_global_load_lds(
      (const __attribute__((address_space(1))) unsigned int*)gsrc,
      (__attribute__((address_space(3))) unsigned int*)lds, 16, 0, 0);
}

// ---------------- fused cast fp32 -> bf16 (x + 4 weights) ----------------
__global__ __launch_bounds__(256) void cast_all(
    const float* __restrict__ x, const float* __restrict__ wq,
    const float* __restrict__ wk, const float* __restrict__ wv,
    const float* __restrict__ wo, ushort* __restrict__ xb,
    ushort* __restrict__ wqb, ushort* __restrict__ wkb,
    ushort* __restrict__ wvb, ushort* __restrict__ wob) {
  const int NX = M_TOT * D / 4;
  const int NW = D * D / 4;
  int i = blockIdx.x * 256 + threadIdx.x;
  const float* src; ushort* dst; int off;
  if (i < NX) { src = x; dst = xb; off = i; }
  else {
    int j = i - NX; int w = j / NW; off = j - w * NW;
    src = (w == 0) ? wq : (w == 1) ? wk : (w == 2) ? wv : wo;
    dst = (w == 0) ? wqb : (w == 1) ? wkb : (w == 2) ? wvb : wob;
  }
  float4 f = reinterpret_cast<const float4*>(src)[off];
  ushort4 u;
  u.x = f2bf(f.x); u.y = f2bf(f.y); u.z = f2bf(f.z); u.w = f2bf(f.w);
  reinterpret_cast<ushort4*>(dst)[off] = u;
}

// ---------------- fused QKV GEMM: 1152 blocks, 128x128 tiles, BK=32 ----------------
// blocks 0..767:  QK fused: m=token, n=feature; y<6 -> Q (*qscale), else K -> [b][h][s][hd]
// blocks 768..1151: V^T:    m=feature, n=token -> [b][h][hd][s]
__global__ __launch_bounds__(256) void gemm_qkv(
    const ushort* __restrict__ xb, const ushort* __restrict__ wqb,
    const ushort* __restrict__ wkb, const ushort* __restrict__ wvb,
    ushort* __restrict__ qb, ushort* __restrict__ kb_,
    ushort* __restrict__ vtb, float qscale) {
  __shared__ ushort SM[2][8192];
  const int tid = threadIdx.x;
  const int lane = tid & 63, wid = tid >> 6;
  const int g = lane >> 4, li = lane & 15;
  const int wm = wid >> 1, wn = wid & 1;

  const int wg = blockIdx.x;
  const ushort *Ap, *Wp; ushort* ob; float osc; int m0, n0; bool vt;
  if (wg < 768) {
    vt = false;
    m0 = (wg & 63) * 128;
    const int y = wg >> 6;
    n0 = (y % 6) * 128;
    Ap = xb;
    if (y < 6) { Wp = wqb; ob = qb; osc = qscale; }
    else       { Wp = wkb; ob = kb_; osc = 1.0f; }
  } else {
    vt = true;
    const int t2 = wg - 768;
    m0 = (t2 % 6) * 128;
    n0 = (t2 / 6) * 128;
    Ap = wvb; Wp = xb; ob = vtb; osc = 1.0f;
  }

  const int rsub = lane >> 2;
  const int coff = (((lane & 3) ^ ((rsub >> 1) & 3)) << 3);

  auto stage = [&](int buf, int k0) {
#pragma unroll
    for (int rnd = 0; rnd < 2; ++rnd) {
      const int row0 = rnd * 64 + wid * 16;
      gload_lds16(&Ap[(size_t)(m0 + row0 + rsub) * 768 + k0 + coff], &SM[buf][row0 * 32]);
      gload_lds16(&Wp[(size_t)(n0 + row0 + rsub) * 768 + k0 + coff],
                  &SM[buf][4096 + row0 * 32]);
    }
  };

  f32x4 acc[4][4] = {};
  stage(0, 0);

  for (int kt = 0; kt < 24; ++kt) {
    const int cur = kt & 1;
    asm volatile("s_waitcnt vmcnt(0)" ::: "memory");
    __syncthreads();
    if (kt + 1 < 24) stage(cur ^ 1, (kt + 1) * 32);

    bf16x8 a[4], b[4];
#pragma unroll
    for (int i = 0; i < 4; ++i) {
      const int row = wm * 64 + i * 16 + li;
      a[i] = *reinterpret_cast<const bf16x8*>(
          &SM[cur][row * 32 + ((g ^ ((row >> 1) & 3)) << 3)]);
    }
#pragma unroll
    for (int j = 0; j < 4; ++j) {
      const int row = wn * 64 + j * 16 + li;
      b[j] = *reinterpret_cast<const bf16x8*>(
          &SM[cur][4096 + row * 32 + ((g ^ ((row >> 1) & 3)) << 3)]);
    }
    __builtin_amdgcn_s_setprio(1);
#pragma unroll
    for (int i = 0; i < 4; ++i)
#pragma unroll
      for (int j = 0; j < 4; ++j)
        acc[i][j] = __builtin_amdgcn_mfma_f32_16x16x32_bf16(a[i], b[j], acc[i][j], 0, 0, 0);
    __builtin_amdgcn_s_setprio(0);
  }

  // ---- bf16 epilogue via LDS round-trip -> 128B-contiguous stores ----
  __syncthreads();
  ushort* Cs = &SM[0][0];
#pragma unroll
  for (int i = 0; i < 4; ++i)
#pragma unroll
    for (int j = 0; j < 4; ++j)
#pragma unroll
      for (int r = 0; r < 4; ++r) {
        const int row = wm * 64 + i * 16 + g * 4 + r;
        const int col = wn * 64 + j * 16 + li;
        const int pc = ((((col >> 3) ^ (row & 7)) << 3) | (col & 7));
        Cs[row * 128 + pc] = f2bf(acc[i][j][r] * osc);
      }
  __syncthreads();

  const int row = tid >> 1, half = tid & 1;
  ushort* dst;
  if (!vt) {
    const int m = m0 + row;
    const int b_ = m >> 11, s_ = m & 2047;
    const int h_ = (n0 >> 6) + half;
    dst = &ob[(((size_t)b_ * H + h_) * S + s_) * HD];
  } else {
    const int mf = m0 + row;
    const int b_ = n0 >> 11;
    const int h_ = mf >> 6, hd_ = mf & 63;
    dst = &ob[(((size_t)b_ * H + h_) * HD + hd_) * S + (n0 & 2047) + half * 64];
  }
#pragma unroll
  for (int c8 = 0; c8 < 8; ++c8) {
    const int col = half * 64 + c8 * 8;
    const int chunk = (col >> 3) ^ (row & 7);
    bf16x8 vv = *reinterpret_cast<const bf16x8*>(&Cs[row * 128 + chunk * 8]);
    *reinterpret_cast<bf16x8*>(&dst[c8 * 8]) = vv;
  }
}

// ---------------- WO GEMM: out = ctx @ wo^T + bias (fp32), 128x128 ----------------
__global__ __launch_bounds__(256) void gemm_wo(const ushort* __restrict__ A,
                                               const ushort* __restrict__ W,
                                               float* __restrict__ out_f,
                                               const float* __restrict__ bias) {
  __shared__ ushort SM[2][8192];
  const int tid = threadIdx.x;
  const int lane = tid & 63, wid = tid >> 6;
  const int g = lane >> 4, li = lane & 15;
  const int wm = wid >> 1, wn = wid & 1;
  const int m0 = blockIdx.x * 128, n0 = blockIdx.y * 128;

  const int rsub = lane >> 2;
  const int coff = (((lane & 3) ^ ((rsub >> 1) & 3)) << 3);

  auto stage = [&](int buf, int k0) {
#pragma unroll
    for (int rnd = 0; rnd < 2; ++rnd) {
      const int row0 = rnd * 64 + wid * 16;
      gload_lds16(&A[(size_t)(m0 + row0 + rsub) * 768 + k0 + coff], &SM[buf][row0 * 32]);
      gload_lds16(&W[(size_t)(n0 + row0 + rsub) * 768 + k0 + coff],
                  &SM[buf][4096 + row0 * 32]);
    }
  };

  f32x4 acc[4][4] = {};
  stage(0, 0);

  for (int kt = 0; kt < 24; ++kt) {
    const int cur = kt & 1;
    asm volatile("s_waitcnt vmcnt(0)" ::: "memory");
    __syncthreads();
    if (kt + 1 < 24) stage(cur ^ 1, (kt + 1) * 32);

    bf16x8 a[4], b[4];
#pragma unroll
    for (int i = 0; i < 4; ++i) {
      const int row = wm * 64 + i * 16 + li;
      a[i] = *reinterpret_cast<const bf16x8*>(
          &SM[cur][row * 32 + ((g ^ ((row >> 1) & 3)) << 3)]);
    }
#pragma unroll
    for (int j = 0; j < 4; ++j) {
      const int row = wn * 64 + j * 16 + li;
      b[j] = *reinterpret_cast<const bf16x8*>(
          &SM[cur][4096 + row * 32 + ((g ^ ((row >> 1) & 3)) << 3)]);
    }
    __builtin_amdgcn_s_setprio(1);
#pragma unroll
    for (int i = 0; i < 4; ++i)
#pragma unroll
      for (int j = 0; j < 4; ++j)
        acc[i][j] = __builtin_amdgcn_mfma_f32_16x16x32_bf16(a[i], b[j], acc[i][j], 0, 0, 0);
    __builtin_amdgcn_s_setprio(0);
  }

#pragma unroll
  for (int i = 0; i < 4; ++i)
#pragma unroll
    for (int j = 0; j < 4; ++j)
#pragma unroll
      for (int r = 0; r < 4; ++r) {
        const int m = m0 + wm * 64 + i * 16 + g * 4 + r;
        const int n = n0 + wn * 64 + j * 16 + li;
        out_f[(size_t)m * 768 + n] = acc[i][j][r] + bias[n];
      }
}

// ---------------- flash attention, 32x32 MFMA, in-register P (no P LDS) ----------------
// Q: [b][h][s][hd] pre-scaled by log2e/8. K: [b][h][s][hd]. VT: [b][h][hd][s].
// ctx: [b][s][h*64+hd] bf16.
// Block = q-tile pair (p, 31-p): waves 0,1 = halves of long tile, 2,3 = short tile.
// Swapped QK^T -> sc[k][q] (q = lane&31); cvt_pk + permlane32_swap builds PV
// B-fragments in-register; PV = mfma(V^T, P) -> C[d][q], lane-local l-normalize.
__global__ __launch_bounds__(256) void attn_kernel(const ushort* __restrict__ Q,
                                                   const ushort* __restrict__ K,
                                                   const ushort* __restrict__ VT,
                                                   ushort* __restrict__ ctx) {
  __shared__ ushort Ks[2][64 * 64];
  __shared__ ushort Vts[2][64 * 64];

  const int tid = threadIdx.x;
  const int lane = tid & 63, wid = tid >> 6;
  const int l31 = lane & 31, hi = lane >> 5;

  // wg -> (xcd, head, p): 6 heads per XCD, 16 pair-blocks per head.
  const int wg = blockIdx.x;
  const int xcd = wg & 7, t = wg >> 3;
  const int bh = xcd + 8 * (t >> 4);
  const int p = t & 15;
  const int qL = 64 * (31 - p), qS = 64 * p;
  const bool isLong = wid < 2;
  const int q0w = isLong ? (qL + 32 * wid) : (qS + 32 * (wid - 2));
  const int q = q0w + l31;                 // this lane's query row
  const int mytrips = isLong ? (32 - p) : (p + 1);
  const int maskkt = isLong ? (31 - p) : p;

  const size_t base = (size_t)bh * S * HD;
  const size_t vtbase = (size_t)bh * HD * S;

  // Q B-fragments: lane holds Q[q][16*ds + 8*hi .. +8]
  bf16x8 qf[4];
#pragma unroll
  for (int ds_ = 0; ds_ < 4; ++ds_)
    qf[ds_] = *reinterpret_cast<const bf16x8*>(
        &Q[base + (size_t)q * HD + 16 * ds_ + 8 * hi]);

  f32x16 acc[2] = {};
  float lpart = 0.f;

  const int nkt = 32 - p;   // block staging trip count (= long-wave trips)

  const int rsub = lane >> 3;
  const int c8e = (((lane & 7) ^ rsub) << 3);

  auto stage = [&](int buf, int k0) {
#pragma unroll
    for (int rnd = 0; rnd < 2; ++rnd) {
      const int row0 = rnd * 32 + wid * 8;
      gload_lds16(&K[base + (size_t)(k0 + row0 + rsub) * HD + c8e], &Ks[buf][row0 << 6]);
      gload_lds16(&VT[vtbase + (size_t)(row0 + rsub) * S + k0 + c8e], &Vts[buf][row0 << 6]);
    }
  };

  stage(0, 0);

  for (int kt = 0; kt < nkt; ++kt) {
    const int cur = kt & 1;
    const int k0 = kt * 64;

    asm volatile("s_waitcnt vmcnt(0)" ::: "memory");
    __syncthreads();
    if (kt + 1 < nkt) stage(cur ^ 1, k0 + 64);
    if (kt >= mytrips) continue;  // done waves keep barrier/stage cadence

    // ---- QK^T: sc[kb] = scores[k = 32kb + krow][q = l31] ----
    f32x16 sc[2];
    __builtin_amdgcn_s_setprio(1);
#pragma unroll
    for (int kb = 0; kb < 2; ++kb) {
      const int row = 32 * kb + l31, r7 = row & 7;
      const ushort* kr = &Ks[cur][row << 6];
      f32x16 z = {};
#pragma unroll
      for (int ds_ = 0; ds_ < 4; ++ds_) {
        bf16x8 ka = *reinterpret_cast<const bf16x8*>(&kr[((2 * ds_ + hi) ^ r7) << 3]);
        z = __builtin_amdgcn_mfma_f32_32x32x16_bf16(ka, qf[ds_], z, 0, 0, 0);
      }
      sc[kb] = z;
    }
    __builtin_amdgcn_s_setprio(0);

    if (kt == maskkt) {
#pragma unroll
      for (int kb = 0; kb < 2; ++kb) {
        const int kbase = k0 + 32 * kb + 4 * hi;
#pragma unroll
        for (int r = 0; r < 16; ++r) {
          const int k = kbase + (r & 3) + 8 * (r >> 2);
          if (k > q) sc[kb][r] = -1e30f;
        }
      }
    }

    // ---- p = exp2(s); pack + permlane32_swap -> in-register PV fragments ----
    bf16x8 pf[4];
#pragma unroll
    for (int kb = 0; kb < 2; ++kb) {
      float pv[16];
#pragma unroll
      for (int r = 0; r < 16; ++r) pv[r] = __builtin_amdgcn_exp2f(sc[kb][r]);
#pragma unroll
      for (int r = 0; r < 16; ++r) lpart += pv[r];
#pragma unroll
      for (int hf = 0; hf < 2; ++hf) {
        uint a = cvt_pk_bf16(pv[8 * hf + 0], pv[8 * hf + 1]);
        uint c = cvt_pk_bf16(pv[8 * hf + 2], pv[8 * hf + 3]);
        uint b2 = cvt_pk_bf16(pv[8 * hf + 4], pv[8 * hf + 5]);
        uint d2 = cvt_pk_bf16(pv[8 * hf + 6], pv[8 * hf + 7]);
        plane32swap(a, b2);
        plane32swap(c, d2);
        uint4 u = {a, c, b2, d2};
        pf[2 * kb + hf] = *reinterpret_cast<const bf16x8*>(&u);
      }
    }

    // ---- PV: acc[db][d,q] += V^T[d][k] * P[k][q] ----
    __builtin_amdgcn_s_setprio(1);
#pragma unroll
    for (int db = 0; db < 2; ++db) {
      const int row = 32 * db + l31, r7 = row & 7;
      const ushort* vr = &Vts[cur][row << 6];
#pragma unroll
      for (int ks2 = 0; ks2 < 4; ++ks2) {
        bf16x8 va = *reinterpret_cast<const bf16x8*>(&vr[((2 * ks2 + hi) ^ r7) << 3]);
        acc[db] = __builtin_amdgcn_mfma_f32_32x32x16_bf16(va, pf[ks2], acc[db], 0, 0, 0);
      }
    }
    __builtin_amdgcn_s_setprio(0);
  }

  // ---- l reduce (one swap) + normalize + store ----
  float l = lpart;
  l += __shfl_xor(l, 32);
  const float inv = 1.0f / l;
  const int b = bh / H, h = bh % H;
  ushort* crow = &ctx[(size_t)(b * S + q) * D + h * HD];
#pragma unroll
  for (int db = 0; db < 2; ++db)
#pragma unroll
    for (int qd = 0; qd < 4; ++qd) {
      uint2 pw;
      pw.x = cvt_pk_bf16(acc[db][4 * qd + 0] * inv, acc[db][4 * qd + 1] * inv);
      pw.y = cvt_pk_bf16(acc[db][4 * qd + 2] * inv, acc[db][4 * qd + 3] * inv);
      *reinterpret_cast<uint2*>(&crow[32 * db + 8 * qd + 4 * hi]) = pw;
    }
}

extern "C" void kernel_launch(void* const* d_in, const int* in_sizes, int n_in,
                              void* d_out, int out_size, void* d_ws, size_t ws_size,
                              hipStream_t stream) {
  (void)in_sizes; (void)n_in; (void)out_size; (void)ws_size;
  const float* x  = (const float*)d_in[0];
  const float* wq = (const float*)d_in[1];
  const float* wk = (const float*)d_in[2];
  const float* wv = (const float*)d_in[3];
  const float* wo = (const float*)d_in[4];
  const float* bo = (const float*)d_in[5];
  float* out = (float*)d_out;

  const size_t xn = (size_t)M_TOT * D;
  const size_t wn = (size_t)D * D;

  ushort* p = (ushort*)d_ws;
  ushort* x_bf  = p; p += xn;
  ushort* wq_bf = p; p += wn;
  ushort* wk_bf = p; p += wn;
  ushort* wv_bf = p; p += wn;
  ushort* wo_bf = p; p += wn;
  ushort* q_bf  = p; p += xn;
  ushort* k_bf  = p; p += xn;
  ushort* vt_bf = p; p += xn;
  ushort* ctx_bf = x_bf;  // alias: x_bf dead after QKV GEMMs

  cast_all<<<8448, 256, 0, stream>>>(x, wq, wk, wv, wo,
                                     x_bf, wq_bf, wk_bf, wv_bf, wo_bf);

  const float QSCALE = 0.125f * 1.44269504f;  // 1/sqrt(64) * log2(e) folded into Q
  gemm_qkv<<<1152, 256, 0, stream>>>(x_bf, wq_bf, wk_bf, wv_bf,
                                     q_bf, k_bf, vt_bf, QSCALE);

  attn_kernel<<<768, 256, 0, stream>>>(q_bf, k_bf, vt_bf, ctx_bf);

  gemm_wo<<<dim3(64, 6), 256, 0, stream>>>(ctx_bf, wo_bf, out, bo);
}

// Round 8
// 140.939 us; speedup vs baseline: 1.0877x; 1.0877x over previous
//
#include <hip/hip_runtime.h>

#define H 12
#define S 2048
#define D 768
#define HD 64
#define BATCH 4
#define M_TOT (BATCH * S)   // 8192

typedef __attribute__((ext_vector_type(8))) short bf16x8;
typedef __attribute__((ext_vector_type(4))) short bf16x4;
typedef __attribute__((ext_vector_type(4))) float f32x4;

// 16x16x16 bf16 MFMA (K=16, A/B = 2 VGPRs). Builtin probe must run only on the
// DEVICE pass: the host pass has no amdgcn builtins (round-7 lesson).
__device__ __forceinline__ f32x4 mfma16(bf16x4 a, bf16x4 b, f32x4 c) {
#if defined(__HIP_DEVICE_COMPILE__)
#if __has_builtin(__builtin_amdgcn_mfma_f32_16x16x16bf16_1k)
  return __builtin_amdgcn_mfma_f32_16x16x16bf16_1k(a, b, c, 0, 0, 0);
#else
  asm volatile("v_mfma_f32_16x16x16_bf16 %0, %1, %2, %0"
               : "+v"(c) : "v"(a), "v"(b));
  return c;
#endif
#else
  (void)a; (void)b;
  return c;
#endif
}

__device__ __forceinline__ ushort f2bf(float f) {
  unsigned int x = __float_as_uint(f);
  x += 0x7fffu + ((x >> 16) & 1u);
  return (ushort)(x >> 16);
}

__device__ __forceinline__ uint cvt_pk_bf16(float lo, float hi) {
  uint r;
  asm("v_cvt_pk_bf16_f32 %0, %1, %2" : "=v"(r) : "v"(lo), "v"(hi));
  return r;
}

__device__ __forceinline__ void gload_lds16(const void* gsrc, void* lds) {
  __builtin_amdgcn_global_load_lds(
      (const __attribute__((address_space(1))) unsigned int*)gsrc,
      (__attribute__((address_space(3))) unsigned int*)lds, 16, 0, 0);
}

// ---------------- fused cast fp32 -> bf16 (x + 4 weights) ----------------
__global__ __launch_bounds__(256) void cast_all(
    const float* __restrict__ x, const float* __restrict__ wq,
    const float* __restrict__ wk, const float* __restrict__ wv,
    const float* __restrict__ wo, ushort* __restrict__ xb,
    ushort* __restrict__ wqb, ushort* __restrict__ wkb,
    ushort* __restrict__ wvb, ushort* __restrict__ wob) {
  const int NX = M_TOT * D / 4;
  const int NW = D * D / 4;
  int i = blockIdx.x * 256 + threadIdx.x;
  const float* src; ushort* dst; int off;
  if (i < NX) { src = x; dst = xb; off = i; }
  else {
    int j = i - NX; int w = j / NW; off = j - w * NW;
    src = (w == 0) ? wq : (w == 1) ? wk : (w == 2) ? wv : wo;
    dst = (w == 0) ? wqb : (w == 1) ? wkb : (w == 2) ? wvb : wob;
  }
  float4 f = reinterpret_cast<const float4*>(src)[off];
  ushort4 u;
  u.x = f2bf(f.x); u.y = f2bf(f.y); u.z = f2bf(f.z); u.w = f2bf(f.w);
  reinterpret_cast<ushort4*>(dst)[off] = u;
}

// ---------------- fused QKV GEMM: 1152 blocks, 128x128 tiles, BK=32 ----------------
__global__ __launch_bounds__(256) void gemm_qkv(
    const ushort* __restrict__ xb, const ushort* __restrict__ wqb,
    const ushort* __restrict__ wkb, const ushort* __restrict__ wvb,
    ushort* __restrict__ qb, ushort* __restrict__ kb_,
    ushort* __restrict__ vtb, float qscale) {
  __shared__ ushort SM[2][8192];
  const int tid = threadIdx.x;
  const int lane = tid & 63, wid = tid >> 6;
  const int g = lane >> 4, li = lane & 15;
  const int wm = wid >> 1, wn = wid & 1;

  const int wg = blockIdx.x;
  const ushort *Ap, *Wp; ushort* ob; float osc; int m0, n0; bool vt;
  if (wg < 768) {
    vt = false;
    m0 = (wg & 63) * 128;
    const int y = wg >> 6;
    n0 = (y % 6) * 128;
    Ap = xb;
    if (y < 6) { Wp = wqb; ob = qb; osc = qscale; }
    else       { Wp = wkb; ob = kb_; osc = 1.0f; }
  } else {
    vt = true;
    const int t2 = wg - 768;
    m0 = (t2 % 6) * 128;
    n0 = (t2 / 6) * 128;
    Ap = wvb; Wp = xb; ob = vtb; osc = 1.0f;
  }

  const int rsub = lane >> 2;
  const int coff = (((lane & 3) ^ ((rsub >> 1) & 3)) << 3);

  auto stage = [&](int buf, int k0) {
#pragma unroll
    for (int rnd = 0; rnd < 2; ++rnd) {
      const int row0 = rnd * 64 + wid * 16;
      gload_lds16(&Ap[(size_t)(m0 + row0 + rsub) * 768 + k0 + coff], &SM[buf][row0 * 32]);
      gload_lds16(&Wp[(size_t)(n0 + row0 + rsub) * 768 + k0 + coff],
                  &SM[buf][4096 + row0 * 32]);
    }
  };

  f32x4 acc[4][4] = {};
  stage(0, 0);

  for (int kt = 0; kt < 24; ++kt) {
    const int cur = kt & 1;
    asm volatile("s_waitcnt vmcnt(0)" ::: "memory");
    __syncthreads();
    if (kt + 1 < 24) stage(cur ^ 1, (kt + 1) * 32);

    bf16x8 a[4], b[4];
#pragma unroll
    for (int i = 0; i < 4; ++i) {
      const int row = wm * 64 + i * 16 + li;
      a[i] = *reinterpret_cast<const bf16x8*>(
          &SM[cur][row * 32 + ((g ^ ((row >> 1) & 3)) << 3)]);
    }
#pragma unroll
    for (int j = 0; j < 4; ++j) {
      const int row = wn * 64 + j * 16 + li;
      b[j] = *reinterpret_cast<const bf16x8*>(
          &SM[cur][4096 + row * 32 + ((g ^ ((row >> 1) & 3)) << 3)]);
    }
    __builtin_amdgcn_s_setprio(1);
#pragma unroll
    for (int i = 0; i < 4; ++i)
#pragma unroll
      for (int j = 0; j < 4; ++j)
        acc[i][j] = __builtin_amdgcn_mfma_f32_16x16x32_bf16(a[i], b[j], acc[i][j], 0, 0, 0);
    __builtin_amdgcn_s_setprio(0);
  }

  // ---- bf16 epilogue via LDS round-trip -> 128B-contiguous stores ----
  __syncthreads();
  ushort* Cs = &SM[0][0];
#pragma unroll
  for (int i = 0; i < 4; ++i)
#pragma unroll
    for (int j = 0; j < 4; ++j)
#pragma unroll
      for (int r = 0; r < 4; ++r) {
        const int row = wm * 64 + i * 16 + g * 4 + r;
        const int col = wn * 64 + j * 16 + li;
        const int pc = ((((col >> 3) ^ (row & 7)) << 3) | (col & 7));
        Cs[row * 128 + pc] = f2bf(acc[i][j][r] * osc);
      }
  __syncthreads();

  const int row = tid >> 1, half = tid & 1;
  ushort* dst;
  if (!vt) {
    const int m = m0 + row;
    const int b_ = m >> 11, s_ = m & 2047;
    const int h_ = (n0 >> 6) + half;
    dst = &ob[(((size_t)b_ * H + h_) * S + s_) * HD];
  } else {
    const int mf = m0 + row;
    const int b_ = n0 >> 11;
    const int h_ = mf >> 6, hd_ = mf & 63;
    dst = &ob[(((size_t)b_ * H + h_) * HD + hd_) * S + (n0 & 2047) + half * 64];
  }
#pragma unroll
  for (int c8 = 0; c8 < 8; ++c8) {
    const int col = half * 64 + c8 * 8;
    const int chunk = (col >> 3) ^ (row & 7);
    bf16x8 vv = *reinterpret_cast<const bf16x8*>(&Cs[row * 128 + chunk * 8]);
    *reinterpret_cast<bf16x8*>(&dst[c8 * 8]) = vv;
  }
}

// ---------------- WO GEMM: out = ctx @ wo^T + bias (fp32), 128x128 ----------------
__global__ __launch_bounds__(256) void gemm_wo(const ushort* __restrict__ A,
                                               const ushort* __restrict__ W,
                                               float* __restrict__ out_f,
                                               const float* __restrict__ bias) {
  __shared__ ushort SM[2][8192];
  const int tid = threadIdx.x;
  const int lane = tid & 63, wid = tid >> 6;
  const int g = lane >> 4, li = lane & 15;
  const int wm = wid >> 1, wn = wid & 1;
  const int m0 = blockIdx.x * 128, n0 = blockIdx.y * 128;

  const int rsub = lane >> 2;
  const int coff = (((lane & 3) ^ ((rsub >> 1) & 3)) << 3);

  auto stage = [&](int buf, int k0) {
#pragma unroll
    for (int rnd = 0; rnd < 2; ++rnd) {
      const int row0 = rnd * 64 + wid * 16;
      gload_lds16(&A[(size_t)(m0 + row0 + rsub) * 768 + k0 + coff], &SM[buf][row0 * 32]);
      gload_lds16(&W[(size_t)(n0 + row0 + rsub) * 768 + k0 + coff],
                  &SM[buf][4096 + row0 * 32]);
    }
  };

  f32x4 acc[4][4] = {};
  stage(0, 0);

  for (int kt = 0; kt < 24; ++kt) {
    const int cur = kt & 1;
    asm volatile("s_waitcnt vmcnt(0)" ::: "memory");
    __syncthreads();
    if (kt + 1 < 24) stage(cur ^ 1, (kt + 1) * 32);

    bf16x8 a[4], b[4];
#pragma unroll
    for (int i = 0; i < 4; ++i) {
      const int row = wm * 64 + i * 16 + li;
      a[i] = *reinterpret_cast<const bf16x8*>(
          &SM[cur][row * 32 + ((g ^ ((row >> 1) & 3)) << 3)]);
    }
#pragma unroll
    for (int j = 0; j < 4; ++j) {
      const int row = wn * 64 + j * 16 + li;
      b[j] = *reinterpret_cast<const bf16x8*>(
          &SM[cur][4096 + row * 32 + ((g ^ ((row >> 1) & 3)) << 3)]);
    }
    __builtin_amdgcn_s_setprio(1);
#pragma unroll
    for (int i = 0; i < 4; ++i)
#pragma unroll
      for (int j = 0; j < 4; ++j)
        acc[i][j] = __builtin_amdgcn_mfma_f32_16x16x32_bf16(a[i], b[j], acc[i][j], 0, 0, 0);
    __builtin_amdgcn_s_setprio(0);
  }

#pragma unroll
  for (int i = 0; i < 4; ++i)
#pragma unroll
    for (int j = 0; j < 4; ++j)
#pragma unroll
      for (int r = 0; r < 4; ++r) {
        const int m = m0 + wm * 64 + i * 16 + g * 4 + r;
        const int n = n0 + wn * 64 + j * 16 + li;
        out_f[(size_t)m * 768 + n] = acc[i][j][r] + bias[n];
      }
}

// ---------------- flash attention: dual-fragment waves, in-register P ----------------
// Q: [b][h][s][hd] pre-scaled by log2e/8. K: [b][h][s][hd]. VT: [b][h][hd][s].
// ctx: [b][s][h*64+hd] bf16.
// Block = q-tile pair (p, 31-p); EVERY wave owns 16 rows of the long tile (f=0,
// active all trips) + 16 rows of the short tile (f=1, active while kt<=p).
// Swapped QK^T C-layout == 16x16x16 A-frag layout after cvt_pk -> P never
// leaves registers; PV = 4 K=16 MFMAs per d-tile against bf16x4 V^T fragments.
__global__ __launch_bounds__(256) void attn_kernel(const ushort* __restrict__ Q,
                                                   const ushort* __restrict__ K,
                                                   const ushort* __restrict__ VT,
                                                   ushort* __restrict__ ctx) {
  __shared__ ushort Ks[2][64 * 64];
  __shared__ ushort Vts[2][64 * 64];   // 32 KB total -> 5 blocks/CU

  const int tid = threadIdx.x;
  const int lane = tid & 63, wid = tid >> 6;
  const int g = lane >> 4, li = lane & 15;

  const int wg = blockIdx.x;
  const int xcd = wg & 7, t = wg >> 3;
  const int bh = xcd + 8 * (t >> 4);
  const int p = t & 15;
  const int qL = 64 * (31 - p), qS = 64 * p;

  const size_t base = (size_t)bh * S * HD;
  const size_t vtbase = (size_t)bh * HD * S;

  bf16x8 aq[2][2];
#pragma unroll
  for (int f = 0; f < 2; ++f) {
    const size_t qr = base + (size_t)((f ? qS : qL) + wid * 16 + li) * HD;
#pragma unroll
    for (int c = 0; c < 2; ++c)
      aq[f][c] = *reinterpret_cast<const bf16x8*>(&Q[qr + c * 32 + g * 8]);
  }

  f32x4 acc[2][4] = {};
  float lpart[2] = {0.f, 0.f};

  const int nkt = 32 - p;

  const int rsub = lane >> 3;
  const int c8e = (((lane & 7) ^ rsub) << 3);

  auto stage = [&](int buf, int k0) {
#pragma unroll
    for (int rnd = 0; rnd < 2; ++rnd) {
      const int row0 = rnd * 32 + wid * 8;
      gload_lds16(&K[base + (size_t)(k0 + row0 + rsub) * HD + c8e], &Ks[buf][row0 << 6]);
      gload_lds16(&VT[vtbase + (size_t)(row0 + rsub) * S + k0 + c8e], &Vts[buf][row0 << 6]);
    }
  };

  stage(0, 0);

  for (int kt = 0; kt < nkt; ++kt) {
    const int cur = kt & 1;
    const int k0 = kt * 64;
    const bool doS = (kt <= p);

    asm volatile("s_waitcnt vmcnt(0)" ::: "memory");
    __syncthreads();
    if (kt + 1 < nkt) stage(cur ^ 1, k0 + 64);

    // ---- QK^T swapped: sc[f][ct] = score(k = 16ct+4g+r, q-local = li) ----
    f32x4 sc[2][4];
    __builtin_amdgcn_s_setprio(1);
#pragma unroll
    for (int ct = 0; ct < 4; ++ct) {
      const int row = ct * 16 + li, r7 = row & 7;
      const ushort* kr = &Ks[cur][row << 6];
      bf16x8 kb0 = *reinterpret_cast<const bf16x8*>(&kr[(g ^ r7) << 3]);
      bf16x8 kb1 = *reinterpret_cast<const bf16x8*>(&kr[((4 + g) ^ r7) << 3]);
      {
        f32x4 z = {};
        z = __builtin_amdgcn_mfma_f32_16x16x32_bf16(kb0, aq[0][0], z, 0, 0, 0);
        z = __builtin_amdgcn_mfma_f32_16x16x32_bf16(kb1, aq[0][1], z, 0, 0, 0);
        sc[0][ct] = z;
      }
      if (doS) {
        f32x4 z = {};
        z = __builtin_amdgcn_mfma_f32_16x16x32_bf16(kb0, aq[1][0], z, 0, 0, 0);
        z = __builtin_amdgcn_mfma_f32_16x16x32_bf16(kb1, aq[1][1], z, 0, 0, 0);
        sc[1][ct] = z;
      }
    }
    __builtin_amdgcn_s_setprio(0);

    if (kt == nkt - 1) {  // f=0 diagonal
      const int q = qL + wid * 16 + li;
#pragma unroll
      for (int ct = 0; ct < 4; ++ct)
#pragma unroll
        for (int r = 0; r < 4; ++r)
          if (k0 + ct * 16 + 4 * g + r > q) sc[0][ct][r] = -1e30f;
    }
    if (kt == p) {  // f=1 diagonal
      const int q = qS + wid * 16 + li;
#pragma unroll
      for (int ct = 0; ct < 4; ++ct)
#pragma unroll
        for (int r = 0; r < 4; ++r)
          if (k0 + ct * 16 + 4 * g + r > q) sc[1][ct][r] = -1e30f;
    }

    // ---- p = exp2(s); cvt_pk pairs ARE the 16x16x16 A-fragments ----
    uint2 pf[2][4];
#pragma unroll
    for (int f = 0; f < 2; ++f) {
      if (f == 1 && !doS) break;
#pragma unroll
      for (int ct = 0; ct < 4; ++ct) {
        float p0 = __builtin_amdgcn_exp2f(sc[f][ct][0]);
        float p1 = __builtin_amdgcn_exp2f(sc[f][ct][1]);
        float p2 = __builtin_amdgcn_exp2f(sc[f][ct][2]);
        float p3 = __builtin_amdgcn_exp2f(sc[f][ct][3]);
        lpart[f] += (p0 + p1) + (p2 + p3);
        pf[f][ct].x = cvt_pk_bf16(p0, p1);
        pf[f][ct].y = cvt_pk_bf16(p2, p3);
      }
    }

    // ---- PV: acc[f][dt] += P-frag x V^T-frag, 4 x (16x16x16) per dt ----
    __builtin_amdgcn_s_setprio(1);
#pragma unroll
    for (int dt = 0; dt < 4; ++dt) {
      const int row = dt * 16 + li, r7 = row & 7;
      const ushort* vr = &Vts[cur][row << 6];
#pragma unroll
      for (int ct = 0; ct < 4; ++ct) {
        const int e = 16 * ct + 4 * g;                       // logical elem offset
        const int phys = (((e >> 3) ^ r7) << 3) + (e & 7);   // swizzled
        bf16x4 vb = *reinterpret_cast<const bf16x4*>(&vr[phys]);
        acc[0][dt] = mfma16(*reinterpret_cast<const bf16x4*>(&pf[0][ct]), vb, acc[0][dt]);
        if (doS)
          acc[1][dt] = mfma16(*reinterpret_cast<const bf16x4*>(&pf[1][ct]), vb, acc[1][dt]);
      }
    }
    __builtin_amdgcn_s_setprio(0);
  }

  // ---- l reduce + normalize + store ----
  const int b = bh / H, h = bh % H;
#pragma unroll
  for (int f = 0; f < 2; ++f) {
    float l = lpart[f];
    l += __shfl_xor(l, 16);
    l += __shfl_xor(l, 32);
#pragma unroll
    for (int r = 0; r < 4; ++r) {
      float inv = 1.0f / __shfl(l, 4 * g + r);
      const int s = (f ? qS : qL) + wid * 16 + 4 * g + r;
#pragma unroll
      for (int dt = 0; dt < 4; ++dt)
        ctx[((size_t)(b * S + s)) * D + h * HD + dt * 16 + li] =
            f2bf(acc[f][dt][r] * inv);
    }
  }
}

extern "C" void kernel_launch(void* const* d_in, const int* in_sizes, int n_in,
                              void* d_out, int out_size, void* d_ws, size_t ws_size,
                              hipStream_t stream) {
  (void)in_sizes; (void)n_in; (void)out_size; (void)ws_size;
  const float* x  = (const float*)d_in[0];
  const float* wq = (const float*)d_in[1];
  const float* wk = (const float*)d_in[2];
  const float* wv = (const float*)d_in[3];
  const float* wo = (const float*)d_in[4];
  const float* bo = (const float*)d_in[5];
  float* out = (float*)d_out;

  const size_t xn = (size_t)M_TOT * D;
  const size_t wn = (size_t)D * D;

  ushort* p = (ushort*)d_ws;
  ushort* x_bf  = p; p += xn;
  ushort* wq_bf = p; p += wn;
  ushort* wk_bf = p; p += wn;
  ushort* wv_bf = p; p += wn;
  ushort* wo_bf = p; p += wn;
  ushort* q_bf  = p; p += xn;
  ushort* k_bf  = p; p += xn;
  ushort* vt_bf = p; p += xn;
  ushort* ctx_bf = x_bf;  // alias: x_bf dead after QKV GEMMs

  cast_all<<<8448, 256, 0, stream>>>(x, wq, wk, wv, wo,
                                     x_bf, wq_bf, wk_bf, wv_bf, wo_bf);

  const float QSCALE = 0.125f * 1.44269504f;  // 1/sqrt(64) * log2(e) folded into Q
  gemm_qkv<<<1152, 256, 0, stream>>>(x_bf, wq_bf, wk_bf, wv_bf,
                                     q_bf, k_bf, vt_bf, QSCALE);

  attn_kernel<<<768, 256, 0, stream>>>(q_bf, k_bf, vt_bf, ctx_bf);

  gemm_wo<<<dim3(64, 6), 256, 0, stream>>>(ctx_bf, wo_bf, out, bo);
}

// Round 9
// 135.407 us; speedup vs baseline: 1.1322x; 1.0409x over previous
//
#include <hip/hip_runtime.h>

#define H 12
#define S 2048
#define D 768
#define HD 64
#define BATCH 4
#define M_TOT (BATCH * S)   // 8192

typedef __attribute__((ext_vector_type(8))) short bf16x8;
typedef __attribute__((ext_vector_type(4))) float f32x4;

__device__ __forceinline__ ushort f2bf(float f) {
  unsigned int x = __float_as_uint(f);
  x += 0x7fffu + ((x >> 16) & 1u);
  return (ushort)(x >> 16);
}

__device__ __forceinline__ uint cvt_pk_bf16(float lo, float hi) {
  uint r;
  asm("v_cvt_pk_bf16_f32 %0, %1, %2" : "=v"(r) : "v"(lo), "v"(hi));
  return r;
}

__device__ __forceinline__ void gload_lds16(const void* gsrc, void* lds) {
  __builtin_amdgcn_global_load_lds(
      (const __attribute__((address_space(1))) unsigned int*)gsrc,
      (__attribute__((address_space(3))) unsigned int*)lds, 16, 0, 0);
}

// ---------------- fused cast fp32 -> bf16 (x + 4 weights) ----------------
__global__ __launch_bounds__(256) void cast_all(
    const float* __restrict__ x, const float* __restrict__ wq,
    const float* __restrict__ wk, const float* __restrict__ wv,
    const float* __restrict__ wo, ushort* __restrict__ xb,
    ushort* __restrict__ wqb, ushort* __restrict__ wkb,
    ushort* __restrict__ wvb, ushort* __restrict__ wob) {
  const int NX = M_TOT * D / 4;
  const int NW = D * D / 4;
  int i = blockIdx.x * 256 + threadIdx.x;
  const float* src; ushort* dst; int off;
  if (i < NX) { src = x; dst = xb; off = i; }
  else {
    int j = i - NX; int w = j / NW; off = j - w * NW;
    src = (w == 0) ? wq : (w == 1) ? wk : (w == 2) ? wv : wo;
    dst = (w == 0) ? wqb : (w == 1) ? wkb : (w == 2) ? wvb : wob;
  }
  float4 f = reinterpret_cast<const float4*>(src)[off];
  ushort4 u;
  u.x = f2bf(f.x); u.y = f2bf(f.y); u.z = f2bf(f.z); u.w = f2bf(f.w);
  reinterpret_cast<ushort4*>(dst)[off] = u;
}

// ---------------- fused QKV GEMM: 1152 blocks, 128x128 tiles, BK=32 ----------------
__global__ __launch_bounds__(256) void gemm_qkv(
    const ushort* __restrict__ xb, const ushort* __restrict__ wqb,
    const ushort* __restrict__ wkb, const ushort* __restrict__ wvb,
    ushort* __restrict__ qb, ushort* __restrict__ kb_,
    ushort* __restrict__ vtb, float qscale) {
  __shared__ ushort SM[2][8192];
  const int tid = threadIdx.x;
  const int lane = tid & 63, wid = tid >> 6;
  const int g = lane >> 4, li = lane & 15;
  const int wm = wid >> 1, wn = wid & 1;

  const int wg = blockIdx.x;
  const ushort *Ap, *Wp; ushort* ob; float osc; int m0, n0; bool vt;
  if (wg < 768) {
    vt = false;
    m0 = (wg & 63) * 128;
    const int y = wg >> 6;
    n0 = (y % 6) * 128;
    Ap = xb;
    if (y < 6) { Wp = wqb; ob = qb; osc = qscale; }
    else       { Wp = wkb; ob = kb_; osc = 1.0f; }
  } else {
    vt = true;
    const int t2 = wg - 768;
    m0 = (t2 % 6) * 128;
    n0 = (t2 / 6) * 128;
    Ap = wvb; Wp = xb; ob = vtb; osc = 1.0f;
  }

  const int rsub = lane >> 2;
  const int coff = (((lane & 3) ^ ((rsub >> 1) & 3)) << 3);

  auto stage = [&](int buf, int k0) {
#pragma unroll
    for (int rnd = 0; rnd < 2; ++rnd) {
      const int row0 = rnd * 64 + wid * 16;
      gload_lds16(&Ap[(size_t)(m0 + row0 + rsub) * 768 + k0 + coff], &SM[buf][row0 * 32]);
      gload_lds16(&Wp[(size_t)(n0 + row0 + rsub) * 768 + k0 + coff],
                  &SM[buf][4096 + row0 * 32]);
    }
  };

  f32x4 acc[4][4] = {};
  stage(0, 0);

  for (int kt = 0; kt < 24; ++kt) {
    const int cur = kt & 1;
    asm volatile("s_waitcnt vmcnt(0)" ::: "memory");
    __syncthreads();
    if (kt + 1 < 24) stage(cur ^ 1, (kt + 1) * 32);

    bf16x8 a[4], b[4];
#pragma unroll
    for (int i = 0; i < 4; ++i) {
      const int row = wm * 64 + i * 16 + li;
      a[i] = *reinterpret_cast<const bf16x8*>(
          &SM[cur][row * 32 + ((g ^ ((row >> 1) & 3)) << 3)]);
    }
#pragma unroll
    for (int j = 0; j < 4; ++j) {
      const int row = wn * 64 + j * 16 + li;
      b[j] = *reinterpret_cast<const bf16x8*>(
          &SM[cur][4096 + row * 32 + ((g ^ ((row >> 1) & 3)) << 3)]);
    }
    __builtin_amdgcn_s_setprio(1);
#pragma unroll
    for (int i = 0; i < 4; ++i)
#pragma unroll
      for (int j = 0; j < 4; ++j)
        acc[i][j] = __builtin_amdgcn_mfma_f32_16x16x32_bf16(a[i], b[j], acc[i][j], 0, 0, 0);
    __builtin_amdgcn_s_setprio(0);
  }

  // ---- bf16 epilogue via LDS round-trip -> 128B-contiguous stores ----
  __syncthreads();
  ushort* Cs = &SM[0][0];
#pragma unroll
  for (int i = 0; i < 4; ++i)
#pragma unroll
    for (int j = 0; j < 4; ++j)
#pragma unroll
      for (int r = 0; r < 4; ++r) {
        const int row = wm * 64 + i * 16 + g * 4 + r;
        const int col = wn * 64 + j * 16 + li;
        const int pc = ((((col >> 3) ^ (row & 7)) << 3) | (col & 7));
        Cs[row * 128 + pc] = f2bf(acc[i][j][r] * osc);
      }
  __syncthreads();

  const int row = tid >> 1, half = tid & 1;
  ushort* dst;
  if (!vt) {
    const int m = m0 + row;
    const int b_ = m >> 11, s_ = m & 2047;
    const int h_ = (n0 >> 6) + half;
    dst = &ob[(((size_t)b_ * H + h_) * S + s_) * HD];
  } else {
    const int mf = m0 + row;
    const int b_ = n0 >> 11;
    const int h_ = mf >> 6, hd_ = mf & 63;
    dst = &ob[(((size_t)b_ * H + h_) * HD + hd_) * S + (n0 & 2047) + half * 64];
  }
#pragma unroll
  for (int c8 = 0; c8 < 8; ++c8) {
    const int col = half * 64 + c8 * 8;
    const int chunk = (col >> 3) ^ (row & 7);
    bf16x8 vv = *reinterpret_cast<const bf16x8*>(&Cs[row * 128 + chunk * 8]);
    *reinterpret_cast<bf16x8*>(&dst[c8 * 8]) = vv;
  }
}

// ---------------- WO GEMM: 64x128 tiles, grid (128,6) = 768 blocks = 3/CU ----------------
__global__ __launch_bounds__(256) void gemm_wo(const ushort* __restrict__ A,
                                               const ushort* __restrict__ W,
                                               float* __restrict__ out_f,
                                               const float* __restrict__ bias) {
  __shared__ ushort SM[2][6144];  // A: 0..2047 (64x32), W: 2048..6143 (128x32)
  const int tid = threadIdx.x;
  const int lane = tid & 63, wid = tid >> 6;
  const int g = lane >> 4, li = lane & 15;
  const int wm = wid >> 1, wn = wid & 1;  // wave: rows wm*32..+31, cols wn*64..+63
  const int m0 = blockIdx.x * 64, n0 = blockIdx.y * 128;

  const int rsub = lane >> 2;
  const int coff = (((lane & 3) ^ ((rsub >> 1) & 3)) << 3);

  auto stage = [&](int buf, int k0) {
    gload_lds16(&A[(size_t)(m0 + wid * 16 + rsub) * 768 + k0 + coff],
                &SM[buf][wid * 16 * 32]);
#pragma unroll
    for (int rnd = 0; rnd < 2; ++rnd) {
      const int row0 = rnd * 64 + wid * 16;
      gload_lds16(&W[(size_t)(n0 + row0 + rsub) * 768 + k0 + coff],
                  &SM[buf][2048 + row0 * 32]);
    }
  };

  f32x4 acc[2][4] = {};
  stage(0, 0);

  for (int kt = 0; kt < 24; ++kt) {
    const int cur = kt & 1;
    asm volatile("s_waitcnt vmcnt(0)" ::: "memory");
    __syncthreads();
    if (kt + 1 < 24) stage(cur ^ 1, (kt + 1) * 32);

    bf16x8 a[2], b[4];
#pragma unroll
    for (int i = 0; i < 2; ++i) {
      const int row = wm * 32 + i * 16 + li;
      a[i] = *reinterpret_cast<const bf16x8*>(
          &SM[cur][row * 32 + ((g ^ ((row >> 1) & 3)) << 3)]);
    }
#pragma unroll
    for (int j = 0; j < 4; ++j) {
      const int row = wn * 64 + j * 16 + li;
      b[j] = *reinterpret_cast<const bf16x8*>(
          &SM[cur][2048 + row * 32 + ((g ^ ((row >> 1) & 3)) << 3)]);
    }
    __builtin_amdgcn_s_setprio(1);
#pragma unroll
    for (int i = 0; i < 2; ++i)
#pragma unroll
      for (int j = 0; j < 4; ++j)
        acc[i][j] = __builtin_amdgcn_mfma_f32_16x16x32_bf16(a[i], b[j], acc[i][j], 0, 0, 0);
    __builtin_amdgcn_s_setprio(0);
  }

#pragma unroll
  for (int i = 0; i < 2; ++i)
#pragma unroll
    for (int j = 0; j < 4; ++j)
#pragma unroll
      for (int r = 0; r < 4; ++r) {
        const int m = m0 + wm * 32 + i * 16 + g * 4 + r;
        const int n = n0 + wn * 64 + j * 16 + li;
        out_f[(size_t)m * 768 + n] = acc[i][j][r] + bias[n];
      }
}

// ---------------- flash attention (round-5 structure): dual-fragment waves ----------------
// Q: [b][h][s][hd] pre-scaled by log2e/8 -> p = exp2(QK^T). K: [b][h][s][hd].
// VT: [b][h][hd][s]. ctx: [b][s][h*64+hd] bf16.
// Block = q-tile pair (p, 31-p); every wave owns 16 long-tile rows (f=0, all trips)
// + 16 short-tile rows (f=1, while kt<=p) -> uniform 33 tile-units per block.
// Swapped QK^T; P through wave-private LDS (Ps) into K=32 PV A-fragments.
__global__ __launch_bounds__(256) void attn_kernel(const ushort* __restrict__ Q,
                                                   const ushort* __restrict__ K,
                                                   const ushort* __restrict__ VT,
                                                   ushort* __restrict__ ctx) {
  __shared__ ushort Ks[2][64 * 64];
  __shared__ ushort Vts[2][64 * 64];
  __shared__ ushort Ps[4][32][72];

  const int tid = threadIdx.x;
  const int lane = tid & 63, wid = tid >> 6;
  const int g = lane >> 4, li = lane & 15;

  const int wg = blockIdx.x;
  const int xcd = wg & 7, t = wg >> 3;
  const int bh = xcd + 8 * (t >> 4);
  const int p = t & 15;
  const int qL = 64 * (31 - p), qS = 64 * p;

  const size_t base = (size_t)bh * S * HD;
  const size_t vtbase = (size_t)bh * HD * S;

  bf16x8 aq[2][2];
#pragma unroll
  for (int f = 0; f < 2; ++f) {
    const size_t qr = base + (size_t)((f ? qS : qL) + wid * 16 + li) * HD;
#pragma unroll
    for (int c = 0; c < 2; ++c)
      aq[f][c] = *reinterpret_cast<const bf16x8*>(&Q[qr + c * 32 + g * 8]);
  }

  f32x4 acc[2][4] = {};
  float lpart[2] = {0.f, 0.f};

  const int nkt = 32 - p;

  const int rsub = lane >> 3;
  const int c8e = (((lane & 7) ^ rsub) << 3);

  auto stage = [&](int buf, int k0) {
#pragma unroll
    for (int rnd = 0; rnd < 2; ++rnd) {
      const int row0 = rnd * 32 + wid * 8;
      gload_lds16(&K[base + (size_t)(k0 + row0 + rsub) * HD + c8e], &Ks[buf][row0 << 6]);
      gload_lds16(&VT[vtbase + (size_t)(row0 + rsub) * S + k0 + c8e], &Vts[buf][row0 << 6]);
    }
  };

  stage(0, 0);

  for (int kt = 0; kt < nkt; ++kt) {
    const int cur = kt & 1;
    const int k0 = kt * 64;
    const bool doS = (kt <= p);

    asm volatile("s_waitcnt vmcnt(0)" ::: "memory");
    __syncthreads();
    if (kt + 1 < nkt) stage(cur ^ 1, k0 + 64);

    // ---- QK^T swapped: sc[f][ct] = score(k = 16ct+4g+r, q-local = li) ----
    f32x4 sc[2][4];
    __builtin_amdgcn_s_setprio(1);
#pragma unroll
    for (int ct = 0; ct < 4; ++ct) {
      const int row = ct * 16 + li, r7 = row & 7;
      const ushort* kr = &Ks[cur][row << 6];
      bf16x8 kb0 = *reinterpret_cast<const bf16x8*>(&kr[(g ^ r7) << 3]);
      bf16x8 kb1 = *reinterpret_cast<const bf16x8*>(&kr[((4 + g) ^ r7) << 3]);
      {
        f32x4 z = {};
        z = __builtin_amdgcn_mfma_f32_16x16x32_bf16(kb0, aq[0][0], z, 0, 0, 0);
        z = __builtin_amdgcn_mfma_f32_16x16x32_bf16(kb1, aq[0][1], z, 0, 0, 0);
        sc[0][ct] = z;
      }
      if (doS) {
        f32x4 z = {};
        z = __builtin_amdgcn_mfma_f32_16x16x32_bf16(kb0, aq[1][0], z, 0, 0, 0);
        z = __builtin_amdgcn_mfma_f32_16x16x32_bf16(kb1, aq[1][1], z, 0, 0, 0);
        sc[1][ct] = z;
      }
    }
    __builtin_amdgcn_s_setprio(0);

    if (kt == nkt - 1) {  // f=0 diagonal
      const int q = qL + wid * 16 + li;
#pragma unroll
      for (int ct = 0; ct < 4; ++ct)
#pragma unroll
        for (int r = 0; r < 4; ++r)
          if (k0 + ct * 16 + 4 * g + r > q) sc[0][ct][r] = -1e30f;
    }
    if (kt == p) {  // f=1 diagonal
      const int q = qS + wid * 16 + li;
#pragma unroll
      for (int ct = 0; ct < 4; ++ct)
#pragma unroll
        for (int r = 0; r < 4; ++r)
          if (k0 + ct * 16 + 4 * g + r > q) sc[1][ct][r] = -1e30f;
    }

    // ---- p = exp2(s), packed bf16 to wave-private LDS ----
#pragma unroll
    for (int f = 0; f < 2; ++f) {
      if (f == 1 && !doS) break;
#pragma unroll
      for (int ct = 0; ct < 4; ++ct) {
        float p0 = __builtin_amdgcn_exp2f(sc[f][ct][0]);
        float p1 = __builtin_amdgcn_exp2f(sc[f][ct][1]);
        float p2 = __builtin_amdgcn_exp2f(sc[f][ct][2]);
        float p3 = __builtin_amdgcn_exp2f(sc[f][ct][3]);
        lpart[f] += (p0 + p1) + (p2 + p3);
        uint2 pw;
        pw.x = cvt_pk_bf16(p0, p1);
        pw.y = cvt_pk_bf16(p2, p3);
        *reinterpret_cast<uint2*>(&Ps[wid][f * 16 + li][ct * 16 + 4 * g]) = pw;
      }
    }

    // ---- PV: A = P rows (K=32 frags), B = V^T rows; vb shared across frags ----
    bf16x8 pa[2][2];
    pa[0][0] = *reinterpret_cast<const bf16x8*>(&Ps[wid][li][g * 8]);
    pa[0][1] = *reinterpret_cast<const bf16x8*>(&Ps[wid][li][32 + g * 8]);
    if (doS) {
      pa[1][0] = *reinterpret_cast<const bf16x8*>(&Ps[wid][16 + li][g * 8]);
      pa[1][1] = *reinterpret_cast<const bf16x8*>(&Ps[wid][16 + li][32 + g * 8]);
    }
    __builtin_amdgcn_s_setprio(1);
#pragma unroll
    for (int dt = 0; dt < 4; ++dt) {
      const int row = dt * 16 + li, r7 = row & 7;
      const ushort* vr = &Vts[cur][row << 6];
      bf16x8 vb0 = *reinterpret_cast<const bf16x8*>(&vr[(g ^ r7) << 3]);
      bf16x8 vb1 = *reinterpret_cast<const bf16x8*>(&vr[((4 + g) ^ r7) << 3]);
      acc[0][dt] = __builtin_amdgcn_mfma_f32_16x16x32_bf16(pa[0][0], vb0, acc[0][dt], 0, 0, 0);
      acc[0][dt] = __builtin_amdgcn_mfma_f32_16x16x32_bf16(pa[0][1], vb1, acc[0][dt], 0, 0, 0);
      if (doS) {
        acc[1][dt] = __builtin_amdgcn_mfma_f32_16x16x32_bf16(pa[1][0], vb0, acc[1][dt], 0, 0, 0);
        acc[1][dt] = __builtin_amdgcn_mfma_f32_16x16x32_bf16(pa[1][1], vb1, acc[1][dt], 0, 0, 0);
      }
    }
    __builtin_amdgcn_s_setprio(0);
  }

  // ---- l reduce + normalize + store ----
  const int b = bh / H, h = bh % H;
#pragma unroll
  for (int f = 0; f < 2; ++f) {
    float l = lpart[f];
    l += __shfl_xor(l, 16);
    l += __shfl_xor(l, 32);
#pragma unroll
    for (int r = 0; r < 4; ++r) {
      float inv = 1.0f / __shfl(l, 4 * g + r);
      const int s = (f ? qS : qL) + wid * 16 + 4 * g + r;
#pragma unroll
      for (int dt = 0; dt < 4; ++dt)
        ctx[((size_t)(b * S + s)) * D + h * HD + dt * 16 + li] =
            f2bf(acc[f][dt][r] * inv);
    }
  }
}

extern "C" void kernel_launch(void* const* d_in, const int* in_sizes, int n_in,
                              void* d_out, int out_size, void* d_ws, size_t ws_size,
                              hipStream_t stream) {
  (void)in_sizes; (void)n_in; (void)out_size; (void)ws_size;
  const float* x  = (const float*)d_in[0];
  const float* wq = (const float*)d_in[1];
  const float* wk = (const float*)d_in[2];
  const float* wv = (const float*)d_in[3];
  const float* wo = (const float*)d_in[4];
  const float* bo = (const float*)d_in[5];
  float* out = (float*)d_out;

  const size_t xn = (size_t)M_TOT * D;
  const size_t wn = (size_t)D * D;

  ushort* p = (ushort*)d_ws;
  ushort* x_bf  = p; p += xn;
  ushort* wq_bf = p; p += wn;
  ushort* wk_bf = p; p += wn;
  ushort* wv_bf = p; p += wn;
  ushort* wo_bf = p; p += wn;
  ushort* q_bf  = p; p += xn;
  ushort* k_bf  = p; p += xn;
  ushort* vt_bf = p; p += xn;
  ushort* ctx_bf = x_bf;  // alias: x_bf dead after QKV GEMMs

  cast_all<<<8448, 256, 0, stream>>>(x, wq, wk, wv, wo,
                                     x_bf, wq_bf, wk_bf, wv_bf, wo_bf);

  const float QSCALE = 0.125f * 1.44269504f;  // 1/sqrt(64) * log2(e) folded into Q
  gemm_qkv<<<1152, 256, 0, stream>>>(x_bf, wq_bf, wk_bf, wv_bf,
                                     q_bf, k_bf, vt_bf, QSCALE);

  attn_kernel<<<768, 256, 0, stream>>>(q_bf, k_bf, vt_bf, ctx_bf);

  gemm_wo<<<dim3(128, 6), 256, 0, stream>>>(ctx_bf, wo_bf, out, bo);
}

// Round 10
// 132.325 us; speedup vs baseline: 1.1586x; 1.0233x over previous
//
#include <hip/hip_runtime.h>

#define H 12
#define S 2048
#define D 768
#define HD 64
#define BATCH 4
#define M_TOT (BATCH * S)   // 8192

typedef __attribute__((ext_vector_type(8))) short bf16x8;
typedef __attribute__((ext_vector_type(4))) float f32x4;

__device__ __forceinline__ ushort f2bf(float f) {
  unsigned int x = __float_as_uint(f);
  x += 0x7fffu + ((x >> 16) & 1u);
  return (ushort)(x >> 16);
}

__device__ __forceinline__ uint cvt_pk_bf16(float lo, float hi) {
  uint r;
  asm("v_cvt_pk_bf16_f32 %0, %1, %2" : "=v"(r) : "v"(lo), "v"(hi));
  return r;
}

__device__ __forceinline__ void gload_lds16(const void* gsrc, void* lds) {
  __builtin_amdgcn_global_load_lds(
      (const __attribute__((address_space(1))) unsigned int*)gsrc,
      (__attribute__((address_space(3))) unsigned int*)lds, 16, 0, 0);
}

// ---------------- fused cast fp32 -> bf16 (x + 4 weights) ----------------
__global__ __launch_bounds__(256) void cast_all(
    const float* __restrict__ x, const float* __restrict__ wq,
    const float* __restrict__ wk, const float* __restrict__ wv,
    const float* __restrict__ wo, ushort* __restrict__ xb,
    ushort* __restrict__ wqb, ushort* __restrict__ wkb,
    ushort* __restrict__ wvb, ushort* __restrict__ wob) {
  const int NX = M_TOT * D / 4;
  const int NW = D * D / 4;
  int i = blockIdx.x * 256 + threadIdx.x;
  const float* src; ushort* dst; int off;
  if (i < NX) { src = x; dst = xb; off = i; }
  else {
    int j = i - NX; int w = j / NW; off = j - w * NW;
    src = (w == 0) ? wq : (w == 1) ? wk : (w == 2) ? wv : wo;
    dst = (w == 0) ? wqb : (w == 1) ? wkb : (w == 2) ? wvb : wob;
  }
  float4 f = reinterpret_cast<const float4*>(src)[off];
  ushort4 u;
  u.x = f2bf(f.x); u.y = f2bf(f.y); u.z = f2bf(f.z); u.w = f2bf(f.w);
  reinterpret_cast<ushort4*>(dst)[off] = u;
}

// ---------------- fused QKV GEMM: 1152 blocks, 128x128, BK=32, 3-deep pipeline ----------------
// Counted vmcnt + raw s_barrier: stage(kt+2) flies across 2 barriers; per-lane
// stage = 4 loads -> steady-state wait vmcnt(4) (stage(kt) landed, stage(kt+1) in flight).
__global__ __launch_bounds__(256) void gemm_qkv(
    const ushort* __restrict__ xb, const ushort* __restrict__ wqb,
    const ushort* __restrict__ wkb, const ushort* __restrict__ wvb,
    ushort* __restrict__ qb, ushort* __restrict__ kb_,
    ushort* __restrict__ vtb, float qscale) {
  __shared__ ushort SM[3][8192];  // 48 KB; C-epilogue reuses SM[0..1]
  const int tid = threadIdx.x;
  const int lane = tid & 63, wid = tid >> 6;
  const int g = lane >> 4, li = lane & 15;
  const int wm = wid >> 1, wn = wid & 1;

  const int wg = blockIdx.x;
  const ushort *Ap, *Wp; ushort* ob; float osc; int m0, n0; bool vt;
  if (wg < 768) {
    vt = false;
    m0 = (wg & 63) * 128;
    const int y = wg >> 6;
    n0 = (y % 6) * 128;
    Ap = xb;
    if (y < 6) { Wp = wqb; ob = qb; osc = qscale; }
    else       { Wp = wkb; ob = kb_; osc = 1.0f; }
  } else {
    vt = true;
    const int t2 = wg - 768;
    m0 = (t2 % 6) * 128;
    n0 = (t2 / 6) * 128;
    Ap = wvb; Wp = xb; ob = vtb; osc = 1.0f;
  }

  const int rsub = lane >> 2;
  const int coff = (((lane & 3) ^ ((rsub >> 1) & 3)) << 3);

  auto stage = [&](int buf, int k0) {
#pragma unroll
    for (int rnd = 0; rnd < 2; ++rnd) {
      const int row0 = rnd * 64 + wid * 16;
      gload_lds16(&Ap[(size_t)(m0 + row0 + rsub) * 768 + k0 + coff], &SM[buf][row0 * 32]);
      gload_lds16(&Wp[(size_t)(n0 + row0 + rsub) * 768 + k0 + coff],
                  &SM[buf][4096 + row0 * 32]);
    }
  };

  f32x4 acc[4][4] = {};
  stage(0, 0);
  stage(1, 32);

  int cur = 0, pre = 2;
  for (int kt = 0; kt < 24; ++kt) {
    // my stage(kt) loads landed (all but newest 4 = stage(kt+1)); lgkm drained
    if (kt < 23) asm volatile("s_waitcnt vmcnt(4) lgkmcnt(0)" ::: "memory");
    else         asm volatile("s_waitcnt vmcnt(0) lgkmcnt(0)" ::: "memory");
    __builtin_amdgcn_s_barrier();   // all waves' stage(kt) landed, prev reads done
    if (kt + 2 < 24) stage(pre, (kt + 2) * 32);  // stays in flight across next barrier

    bf16x8 a[4], b[4];
#pragma unroll
    for (int i = 0; i < 4; ++i) {
      const int row = wm * 64 + i * 16 + li;
      a[i] = *reinterpret_cast<const bf16x8*>(
          &SM[cur][row * 32 + ((g ^ ((row >> 1) & 3)) << 3)]);
    }
#pragma unroll
    for (int j = 0; j < 4; ++j) {
      const int row = wn * 64 + j * 16 + li;
      b[j] = *reinterpret_cast<const bf16x8*>(
          &SM[cur][4096 + row * 32 + ((g ^ ((row >> 1) & 3)) << 3)]);
    }
    __builtin_amdgcn_s_setprio(1);
#pragma unroll
    for (int i = 0; i < 4; ++i)
#pragma unroll
      for (int j = 0; j < 4; ++j)
        acc[i][j] = __builtin_amdgcn_mfma_f32_16x16x32_bf16(a[i], b[j], acc[i][j], 0, 0, 0);
    __builtin_amdgcn_s_setprio(0);

    cur = (cur == 2) ? 0 : cur + 1;
    pre = (pre == 2) ? 0 : pre + 1;
  }

  // ---- bf16 epilogue via LDS round-trip (Cs = SM[0..1], 32 KB) ----
  __syncthreads();
  ushort* Cs = &SM[0][0];
#pragma unroll
  for (int i = 0; i < 4; ++i)
#pragma unroll
    for (int j = 0; j < 4; ++j)
#pragma unroll
      for (int r = 0; r < 4; ++r) {
        const int row = wm * 64 + i * 16 + g * 4 + r;
        const int col = wn * 64 + j * 16 + li;
        const int pc = ((((col >> 3) ^ (row & 7)) << 3) | (col & 7));
        Cs[row * 128 + pc] = f2bf(acc[i][j][r] * osc);
      }
  __syncthreads();

  const int row = tid >> 1, half = tid & 1;
  ushort* dst;
  if (!vt) {
    const int m = m0 + row;
    const int b_ = m >> 11, s_ = m & 2047;
    const int h_ = (n0 >> 6) + half;
    dst = &ob[(((size_t)b_ * H + h_) * S + s_) * HD];
  } else {
    const int mf = m0 + row;
    const int b_ = n0 >> 11;
    const int h_ = mf >> 6, hd_ = mf & 63;
    dst = &ob[(((size_t)b_ * H + h_) * HD + hd_) * S + (n0 & 2047) + half * 64];
  }
#pragma unroll
  for (int c8 = 0; c8 < 8; ++c8) {
    const int col = half * 64 + c8 * 8;
    const int chunk = (col >> 3) ^ (row & 7);
    bf16x8 vv = *reinterpret_cast<const bf16x8*>(&Cs[row * 128 + chunk * 8]);
    *reinterpret_cast<bf16x8*>(&dst[c8 * 8]) = vv;
  }
}

// ---------------- WO GEMM: 64x128 tiles, 768 blocks, 3-deep pipeline ----------------
// Per-lane stage = 3 loads -> steady-state wait vmcnt(3).
__global__ __launch_bounds__(256) void gemm_wo(const ushort* __restrict__ A,
                                               const ushort* __restrict__ W,
                                               float* __restrict__ out_f,
                                               const float* __restrict__ bias) {
  __shared__ ushort SM[3][6144];  // per buf: A 0..2047 (64x32), W 2048..6143 (128x32)
  const int tid = threadIdx.x;
  const int lane = tid & 63, wid = tid >> 6;
  const int g = lane >> 4, li = lane & 15;
  const int wm = wid >> 1, wn = wid & 1;
  const int m0 = blockIdx.x * 64, n0 = blockIdx.y * 128;

  const int rsub = lane >> 2;
  const int coff = (((lane & 3) ^ ((rsub >> 1) & 3)) << 3);

  auto stage = [&](int buf, int k0) {
    gload_lds16(&A[(size_t)(m0 + wid * 16 + rsub) * 768 + k0 + coff],
                &SM[buf][wid * 16 * 32]);
#pragma unroll
    for (int rnd = 0; rnd < 2; ++rnd) {
      const int row0 = rnd * 64 + wid * 16;
      gload_lds16(&W[(size_t)(n0 + row0 + rsub) * 768 + k0 + coff],
                  &SM[buf][2048 + row0 * 32]);
    }
  };

  f32x4 acc[2][4] = {};
  stage(0, 0);
  stage(1, 32);

  int cur = 0, pre = 2;
  for (int kt = 0; kt < 24; ++kt) {
    if (kt < 23) asm volatile("s_waitcnt vmcnt(3) lgkmcnt(0)" ::: "memory");
    else         asm volatile("s_waitcnt vmcnt(0) lgkmcnt(0)" ::: "memory");
    __builtin_amdgcn_s_barrier();
    if (kt + 2 < 24) stage(pre, (kt + 2) * 32);

    bf16x8 a[2], b[4];
#pragma unroll
    for (int i = 0; i < 2; ++i) {
      const int row = wm * 32 + i * 16 + li;
      a[i] = *reinterpret_cast<const bf16x8*>(
          &SM[cur][row * 32 + ((g ^ ((row >> 1) & 3)) << 3)]);
    }
#pragma unroll
    for (int j = 0; j < 4; ++j) {
      const int row = wn * 64 + j * 16 + li;
      b[j] = *reinterpret_cast<const bf16x8*>(
          &SM[cur][2048 + row * 32 + ((g ^ ((row >> 1) & 3)) << 3)]);
    }
    __builtin_amdgcn_s_setprio(1);
#pragma unroll
    for (int i = 0; i < 2; ++i)
#pragma unroll
      for (int j = 0; j < 4; ++j)
        acc[i][j] = __builtin_amdgcn_mfma_f32_16x16x32_bf16(a[i], b[j], acc[i][j], 0, 0, 0);
    __builtin_amdgcn_s_setprio(0);

    cur = (cur == 2) ? 0 : cur + 1;
    pre = (pre == 2) ? 0 : pre + 1;
  }

#pragma unroll
  for (int i = 0; i < 2; ++i)
#pragma unroll
    for (int j = 0; j < 4; ++j)
#pragma unroll
      for (int r = 0; r < 4; ++r) {
        const int m = m0 + wm * 32 + i * 16 + g * 4 + r;
        const int n = n0 + wn * 64 + j * 16 + li;
        out_f[(size_t)m * 768 + n] = acc[i][j][r] + bias[n];
      }
}

// ---------------- flash attention (round-5 structure): dual-fragment waves ----------------
// Q: [b][h][s][hd] pre-scaled by log2e/8 -> p = exp2(QK^T). K: [b][h][s][hd].
// VT: [b][h][hd][s]. ctx: [b][s][h*64+hd] bf16.
// Block = q-tile pair (p, 31-p); every wave owns 16 long-tile rows (f=0, all trips)
// + 16 short-tile rows (f=1, while kt<=p) -> uniform 33 tile-units per block.
__global__ __launch_bounds__(256) void attn_kernel(const ushort* __restrict__ Q,
                                                   const ushort* __restrict__ K,
                                                   const ushort* __restrict__ VT,
                                                   ushort* __restrict__ ctx) {
  __shared__ ushort Ks[2][64 * 64];
  __shared__ ushort Vts[2][64 * 64];
  __shared__ ushort Ps[4][32][72];

  const int tid = threadIdx.x;
  const int lane = tid & 63, wid = tid >> 6;
  const int g = lane >> 4, li = lane & 15;

  const int wg = blockIdx.x;
  const int xcd = wg & 7, t = wg >> 3;
  const int bh = xcd + 8 * (t >> 4);
  const int p = t & 15;
  const int qL = 64 * (31 - p), qS = 64 * p;

  const size_t base = (size_t)bh * S * HD;
  const size_t vtbase = (size_t)bh * HD * S;

  bf16x8 aq[2][2];
#pragma unroll
  for (int f = 0; f < 2; ++f) {
    const size_t qr = base + (size_t)((f ? qS : qL) + wid * 16 + li) * HD;
#pragma unroll
    for (int c = 0; c < 2; ++c)
      aq[f][c] = *reinterpret_cast<const bf16x8*>(&Q[qr + c * 32 + g * 8]);
  }

  f32x4 acc[2][4] = {};
  float lpart[2] = {0.f, 0.f};

  const int nkt = 32 - p;

  const int rsub = lane >> 3;
  const int c8e = (((lane & 7) ^ rsub) << 3);

  auto stage = [&](int buf, int k0) {
#pragma unroll
    for (int rnd = 0; rnd < 2; ++rnd) {
      const int row0 = rnd * 32 + wid * 8;
      gload_lds16(&K[base + (size_t)(k0 + row0 + rsub) * HD + c8e], &Ks[buf][row0 << 6]);
      gload_lds16(&VT[vtbase + (size_t)(row0 + rsub) * S + k0 + c8e], &Vts[buf][row0 << 6]);
    }
  };

  stage(0, 0);

  for (int kt = 0; kt < nkt; ++kt) {
    const int cur = kt & 1;
    const int k0 = kt * 64;
    const bool doS = (kt <= p);

    asm volatile("s_waitcnt vmcnt(0)" ::: "memory");
    __syncthreads();
    if (kt + 1 < nkt) stage(cur ^ 1, k0 + 64);

    // ---- QK^T swapped: sc[f][ct] = score(k = 16ct+4g+r, q-local = li) ----
    f32x4 sc[2][4];
    __builtin_amdgcn_s_setprio(1);
#pragma unroll
    for (int ct = 0; ct < 4; ++ct) {
      const int row = ct * 16 + li, r7 = row & 7;
      const ushort* kr = &Ks[cur][row << 6];
      bf16x8 kb0 = *reinterpret_cast<const bf16x8*>(&kr[(g ^ r7) << 3]);
      bf16x8 kb1 = *reinterpret_cast<const bf16x8*>(&kr[((4 + g) ^ r7) << 3]);
      {
        f32x4 z = {};
        z = __builtin_amdgcn_mfma_f32_16x16x32_bf16(kb0, aq[0][0], z, 0, 0, 0);
        z = __builtin_amdgcn_mfma_f32_16x16x32_bf16(kb1, aq[0][1], z, 0, 0, 0);
        sc[0][ct] = z;
      }
      if (doS) {
        f32x4 z = {};
        z = __builtin_amdgcn_mfma_f32_16x16x32_bf16(kb0, aq[1][0], z, 0, 0, 0);
        z = __builtin_amdgcn_mfma_f32_16x16x32_bf16(kb1, aq[1][1], z, 0, 0, 0);
        sc[1][ct] = z;
      }
    }
    __builtin_amdgcn_s_setprio(0);

    if (kt == nkt - 1) {  // f=0 diagonal
      const int q = qL + wid * 16 + li;
#pragma unroll
      for (int ct = 0; ct < 4; ++ct)
#pragma unroll
        for (int r = 0; r < 4; ++r)
          if (k0 + ct * 16 + 4 * g + r > q) sc[0][ct][r] = -1e30f;
    }
    if (kt == p) {  // f=1 diagonal
      const int q = qS + wid * 16 + li;
#pragma unroll
      for (int ct = 0; ct < 4; ++ct)
#pragma unroll
        for (int r = 0; r < 4; ++r)
          if (k0 + ct * 16 + 4 * g + r > q) sc[1][ct][r] = -1e30f;
    }

    // ---- p = exp2(s), packed bf16 to wave-private LDS ----
#pragma unroll
    for (int f = 0; f < 2; ++f) {
      if (f == 1 && !doS) break;
#pragma unroll
      for (int ct = 0; ct < 4; ++ct) {
        float p0 = __builtin_amdgcn_exp2f(sc[f][ct][0]);
        float p1 = __builtin_amdgcn_exp2f(sc[f][ct][1]);
        float p2 = __builtin_amdgcn_exp2f(sc[f][ct][2]);
        float p3 = __builtin_amdgcn_exp2f(sc[f][ct][3]);
        lpart[f] += (p0 + p1) + (p2 + p3);
        uint2 pw;
        pw.x = cvt_pk_bf16(p0, p1);
        pw.y = cvt_pk_bf16(p2, p3);
        *reinterpret_cast<uint2*>(&Ps[wid][f * 16 + li][ct * 16 + 4 * g]) = pw;
      }
    }

    // ---- PV: A = P rows (K=32 frags), B = V^T rows; vb shared across frags ----
    bf16x8 pa[2][2];
    pa[0][0] = *reinterpret_cast<const bf16x8*>(&Ps[wid][li][g * 8]);
    pa[0][1] = *reinterpret_cast<const bf16x8*>(&Ps[wid][li][32 + g * 8]);
    if (doS) {
      pa[1][0] = *reinterpret_cast<const bf16x8*>(&Ps[wid][16 + li][g * 8]);
      pa[1][1] = *reinterpret_cast<const bf16x8*>(&Ps[wid][16 + li][32 + g * 8]);
    }
    __builtin_amdgcn_s_setprio(1);
#pragma unroll
    for (int dt = 0; dt < 4; ++dt) {
      const int row = dt * 16 + li, r7 = row & 7;
      const ushort* vr = &Vts[cur][row << 6];
      bf16x8 vb0 = *reinterpret_cast<const bf16x8*>(&vr[(g ^ r7) << 3]);
      bf16x8 vb1 = *reinterpret_cast<const bf16x8*>(&vr[((4 + g) ^ r7) << 3]);
      acc[0][dt] = __builtin_amdgcn_mfma_f32_16x16x32_bf16(pa[0][0], vb0, acc[0][dt], 0, 0, 0);
      acc[0][dt] = __builtin_amdgcn_mfma_f32_16x16x32_bf16(pa[0][1], vb1, acc[0][dt], 0, 0, 0);
      if (doS) {
        acc[1][dt] = __builtin_amdgcn_mfma_f32_16x16x32_bf16(pa[1][0], vb0, acc[1][dt], 0, 0, 0);
        acc[1][dt] = __builtin_amdgcn_mfma_f32_16x16x32_bf16(pa[1][1], vb1, acc[1][dt], 0, 0, 0);
      }
    }
    __builtin_amdgcn_s_setprio(0);
  }

  // ---- l reduce + normalize + store ----
  const int b = bh / H, h = bh % H;
#pragma unroll
  for (int f = 0; f < 2; ++f) {
    float l = lpart[f];
    l += __shfl_xor(l, 16);
    l += __shfl_xor(l, 32);
#pragma unroll
    for (int r = 0; r < 4; ++r) {
      float inv = 1.0f / __shfl(l, 4 * g + r);
      const int s = (f ? qS : qL) + wid * 16 + 4 * g + r;
#pragma unroll
      for (int dt = 0; dt < 4; ++dt)
        ctx[((size_t)(b * S + s)) * D + h * HD + dt * 16 + li] =
            f2bf(acc[f][dt][r] * inv);
    }
  }
}

extern "C" void kernel_launch(void* const* d_in, const int* in_sizes, int n_in,
                              void* d_out, int out_size, void* d_ws, size_t ws_size,
                              hipStream_t stream) {
  (void)in_sizes; (void)n_in; (void)out_size; (void)ws_size;
  const float* x  = (const float*)d_in[0];
  const float* wq = (const float*)d_in[1];
  const float* wk = (const float*)d_in[2];
  const float* wv = (const float*)d_in[3];
  const float* wo = (const float*)d_in[4];
  const float* bo = (const float*)d_in[5];
  float* out = (float*)d_out;

  const size_t xn = (size_t)M_TOT * D;
  const size_t wn = (size_t)D * D;

  ushort* p = (ushort*)d_ws;
  ushort* x_bf  = p; p += xn;
  ushort* wq_bf = p; p += wn;
  ushort* wk_bf = p; p += wn;
  ushort* wv_bf = p; p += wn;
  ushort* wo_bf = p; p += wn;
  ushort* q_bf  = p; p += xn;
  ushort* k_bf  = p; p += xn;
  ushort* vt_bf = p; p += xn;
  ushort* ctx_bf = x_bf;  // alias: x_bf dead after QKV GEMMs

  cast_all<<<8448, 256, 0, stream>>>(x, wq, wk, wv, wo,
                                     x_bf, wq_bf, wk_bf, wv_bf, wo_bf);

  const float QSCALE = 0.125f * 1.44269504f;  // 1/sqrt(64) * log2(e) folded into Q
  gemm_qkv<<<1152, 256, 0, stream>>>(x_bf, wq_bf, wk_bf, wv_bf,
                                     q_bf, k_bf, vt_bf, QSCALE);

  attn_kernel<<<768, 256, 0, stream>>>(q_bf, k_bf, vt_bf, ctx_bf);

  gemm_wo<<<dim3(128, 6), 256, 0, stream>>>(ctx_bf, wo_bf, out, bo);
}